// Round 8
// baseline (313.130 us; speedup 1.0000x reference)
//
#include <hip/hip_runtime.h>

// B=4, S=2048, D=1024, H=16, Hd=64. All matmuls bf16 MFMA (16x16x32), fp32 accum.
// ws layout (bytes):
//   xb    @ 0   : bf16 x [8192,1024]            16 MB
//   wt[4] @ 16M : bf16 W^T (q,k,v,o) [1024,1024] 2 MB each (q,k,v CONTIGUOUS = [3072][1024])
//   qb    @ 24M : bf16 Q*(0.125*log2e) [bh][s][hd] 16 MB
//   kb    @ 40M : bf16 K [bh][s][hd]             16 MB
//   vtb   @ 56M : bf16 V^T [bh][hd][s]           16 MB
//   hb    @ 72M : bf16 heads [b*s][1024]         16 MB

typedef __attribute__((ext_vector_type(8))) short bf16x8;
typedef __attribute__((ext_vector_type(4))) float f32x4;
typedef __attribute__((ext_vector_type(4))) unsigned int u32x4;

#define MFMA16 __builtin_amdgcn_mfma_f32_16x16x32_bf16

__device__ __forceinline__ unsigned short f2bf(float f) {
  unsigned int u = __float_as_uint(f);
  u += 0x7fff + ((u >> 16) & 1);   // RNE
  return (unsigned short)(u >> 16);
}

// pack 2 f32 -> 1 u32 of 2 bf16, EXPLICIT order: bf16(lo) in [15:0], bf16(hi) in [31:16].
// Round-half-up (+0x8000). v_perm_b32 sel 0x07060302 = {hi.top16, lo.top16}.
__device__ __forceinline__ unsigned int pkbf(float lo, float hi) {
  unsigned int a = __float_as_uint(lo) + 0x8000u;
  unsigned int b = __float_as_uint(hi) + 0x8000u;
  return __builtin_amdgcn_perm(b, a, 0x07060302u);
}

__device__ __forceinline__ bf16x8 pack4(unsigned int a, unsigned int b,
                                        unsigned int c, unsigned int d) {
  union { u32x4 u; bf16x8 v; } t;
  t.u = (u32x4){a, b, c, d};
  return t.v;
}

// async global->LDS; LDS dest = wave-uniform base + lane*size
__device__ __forceinline__ void gl2l16(const unsigned short* g, unsigned short* l) {
  __builtin_amdgcn_global_load_lds((const __attribute__((address_space(1))) void*)g,
                                   (__attribute__((address_space(3))) void*)l, 16, 0, 0);
}
__device__ __forceinline__ void gl2l4(const unsigned short* g, unsigned short* l) {
  __builtin_amdgcn_global_load_lds((const __attribute__((address_space(1))) void*)g,
                                   (__attribute__((address_space(3))) void*)l, 4, 0, 0);
}

// ---------------- fused prep: convert x + transpose weights (one launch) ----------------
__global__ __launch_bounds__(256) void k_prep(const float* __restrict__ x,
                                              unsigned short* __restrict__ xb,
                                              const float* w0, const float* w1,
                                              const float* w2, const float* w3,
                                              unsigned short* o0, unsigned short* o1,
                                              unsigned short* o2, unsigned short* o3) {
  const int bid = blockIdx.x, tid = threadIdx.x;
  if (bid < 8192) {
    int i = (bid * 256 + tid) * 4;
    float4 v = *(const float4*)(x + i);
    ushort4 u;
    u.x = f2bf(v.x); u.y = f2bf(v.y); u.z = f2bf(v.z); u.w = f2bf(v.w);
    *(ushort4*)(xb + i) = u;
  } else {
    __shared__ float t[32][33];
    int tt = bid - 8192;
    int z = tt >> 10, rem = tt & 1023;
    const float* W = z == 0 ? w0 : z == 1 ? w1 : z == 2 ? w2 : w3;
    unsigned short* O = z == 0 ? o0 : z == 1 ? o1 : z == 2 ? o2 : o3;
    int e0 = (rem & 31) * 32, d0 = (rem >> 5) * 32;
    int tx = tid & 31, ty = tid >> 5;   // 32 x 8
    #pragma unroll
    for (int i = 0; i < 4; i++)
      t[ty + i * 8][tx] = W[(d0 + ty + i * 8) * 1024 + e0 + tx];
    __syncthreads();
    #pragma unroll
    for (int i = 0; i < 4; i++)
      O[(e0 + ty + i * 8) * 1024 + d0 + tx] = f2bf(t[tx][ty + i * 8]);
  }
}

// ---------------- 256x256 8-phase GEMM K-loop (counted vmcnt, raw s_barrier) --------------
// 8 waves (2M x 4N), BK=64, 16 K-tiles (K=1024), 2 tiles/iteration, 8 phases/iteration.
// LDS: A[2][256*64] + B[2][256*64] = 128 KB (1 block/CU, 2 waves/SIMD).
// Per phase: {4 ds_read_b128 af (+8 bf at q==0) | 2 gl2l16 stage | s_barrier |
//             setprio(1) 16 MFMA setprio(0) | [vmcnt(4) at p3/p7] | s_barrier}.
// Per-wave stage stream (2 loads/phase): p0,p1=A(2i+1)->A[1]; p2,p3=B(2i+2)->B[0];
// p4,p5=A(2i+2)->A[0]; p6,p7=B(2i+3)->B[1].  Slot-safety (each verified):
//   A[0] last read ph3 (lgkm-drained before its closing barrier) < staged p4.
//   B[0] last read ph0 (bq hoisted) < staged p2.  A[1]/B[1] mirror at ph4-7.
// vmcnt(4) at p3: all but p2,p3's 4 landed -> A(2i+1) + prev-iter B(2i+1) ready for ph4.
// vmcnt(4) at p7: all but p6,p7's 4 landed -> A,B(2i+2) ready for next iter ph0.
// i==7 p3 uses vmcnt(0): p2,p3 staged nothing so the 4 in-flight would be A(15), needed.
// NEVER __syncthreads here (drains vmcnt(0) incl. prefetch -- the R4 regression).
__device__ __forceinline__ void kloop256(const unsigned short* __restrict__ gA,
                                         const unsigned short* __restrict__ gB,
                                         unsigned short* As, unsigned short* Bs,
                                         int w, int fm, int quad,
                                         f32x4 (&acc)[8][4]) {
  const int fsw = fm & 7;
  const int wm128 = (w >> 2) * 128;
  const int wn64 = (w & 3) * 64;
  const int c0 = (quad ^ fsw) * 8;        // kh=0 slot offset
  const int c1 = ((4 + quad) ^ fsw) * 8;  // kh=1 slot offset

#define STA(t, j) gl2l16(gA + (t) * 64 + (j) * 8192, As + ((t) & 1) * 16384 + w * 2048 + (j) * 512)
#define STB(t, j) gl2l16(gB + (t) * 64 + (j) * 8192, Bs + ((t) & 1) * 16384 + w * 2048 + (j) * 512)

  // prologue: A(0)->A[0], B(0)->B[0], B(1)->B[1]; wait tile0 (first 8), B(1) may fly
  #pragma unroll
  for (int j = 0; j < 4; ++j) STA(0, j);
  #pragma unroll
  for (int j = 0; j < 4; ++j) STB(0, j);
  #pragma unroll
  for (int j = 0; j < 4; ++j) STB(1, j);
  asm volatile("s_waitcnt vmcnt(4)" ::: "memory");
  asm volatile("s_barrier" ::: "memory");

  for (int i = 0; i < 8; ++i) {
    const int t0 = 2 * i, t1 = 2 * i + 1;
    #pragma unroll
    for (int par = 0; par < 2; ++par) {
      const unsigned short* Ap = As + par * 16384;
      const unsigned short* Bp = Bs + par * 16384;
      // hoisted B frags for this tile (read in phase-0 region of the tile)
      bf16x8 bq[4][2];
      #pragma unroll
      for (int nt = 0; nt < 4; ++nt) {
        const int br = (wn64 + nt * 16 + fm) * 64;
        bq[nt][0] = *(const bf16x8*)&Bp[br + c0];
        bq[nt][1] = *(const bf16x8*)&Bp[br + c1];
      }
      #pragma unroll
      for (int q = 0; q < 4; ++q) {
        const int r0 = (wm128 + (2 * q) * 16 + fm) * 64;
        const int r1 = (wm128 + (2 * q + 1) * 16 + fm) * 64;
        bf16x8 a0k0 = *(const bf16x8*)&Ap[r0 + c0];
        bf16x8 a0k1 = *(const bf16x8*)&Ap[r0 + c1];
        bf16x8 a1k0 = *(const bf16x8*)&Ap[r1 + c0];
        bf16x8 a1k1 = *(const bf16x8*)&Ap[r1 + c1];
        // stage (2 loads; uniform guards; slot-safe per header comment)
        if (par == 0) {
          if (q == 0)      { STA(t1, 0); STA(t1, 1); }
          else if (q == 1) { STA(t1, 2); STA(t1, 3); }
          else if (q == 2) { if (i < 7) { STB(t0 + 2, 0); STB(t0 + 2, 1); } }
          else             { if (i < 7) { STB(t0 + 2, 2); STB(t0 + 2, 3); } }
        } else {
          if (q == 0)      { if (i < 7) { STA(t0 + 2, 0); STA(t0 + 2, 1); } }
          else if (q == 1) { if (i < 7) { STA(t0 + 2, 2); STA(t0 + 2, 3); } }
          else if (q == 2) { if (i < 7) { STB(t1 + 2, 0); STB(t1 + 2, 1); } }
          else             { if (i < 7) { STB(t1 + 2, 2); STB(t1 + 2, 3); } }
        }
        asm volatile("s_barrier" ::: "memory");
        __builtin_amdgcn_s_setprio(1);
        #pragma unroll
        for (int nt = 0; nt < 4; ++nt) {
          acc[2 * q][nt]     = MFMA16(a0k0, bq[nt][0], acc[2 * q][nt], 0, 0, 0);
          acc[2 * q][nt]     = MFMA16(a0k1, bq[nt][1], acc[2 * q][nt], 0, 0, 0);
          acc[2 * q + 1][nt] = MFMA16(a1k0, bq[nt][0], acc[2 * q + 1][nt], 0, 0, 0);
          acc[2 * q + 1][nt] = MFMA16(a1k1, bq[nt][1], acc[2 * q + 1][nt], 0, 0, 0);
        }
        __builtin_amdgcn_s_setprio(0);
        if (par == 0 && q == 3) {
          if (i < 7) asm volatile("s_waitcnt vmcnt(4)" ::: "memory");
          else       asm volatile("s_waitcnt vmcnt(0)" ::: "memory");
        }
        if (par == 1 && q == 3)
          asm volatile("s_waitcnt vmcnt(4)" ::: "memory");
        asm volatile("s_barrier" ::: "memory");
      }
    }
  }
#undef STA
#undef STB
}

// ---------------- fused QKV GEMM: 256x256 tiles over N=3072 contiguous W^T ---------------
// Grid 384 blocks, 512 threads. bx = bid%12 (x-fastest: co-resident blocks share A panels).
__global__ __launch_bounds__(512, 2) void gemm_qkv(const unsigned short* __restrict__ A,
                                                   const unsigned short* __restrict__ Wt,
                                                   const float* __restrict__ biq,
                                                   const float* __restrict__ bik,
                                                   const float* __restrict__ biv,
                                                   unsigned short* __restrict__ oq,
                                                   unsigned short* __restrict__ ok,
                                                   unsigned short* __restrict__ ov,
                                                   float qscale) {
  const int bid = blockIdx.x;
  const int bx = bid % 12, by = bid / 12;
  const int bm0 = by * 256;
  const int bn0g = bx * 256;                    // [0,3072), never straddles a z boundary
  const int z = bn0g >> 10, bn0 = bn0g & 1023;

  const float* bias = z == 0 ? biq : z == 1 ? bik : biv;
  unsigned short* out = z == 0 ? oq : z == 1 ? ok : ov;
  const float scale = z == 0 ? qscale : 1.0f;

  const int tid = threadIdx.x;
  const int lane = tid & 63, w = tid >> 6;      // 8 waves
  const int fm = lane & 15, quad = lane >> 4;
  const int wm128 = (w >> 2) * 128, wn64 = (w & 3) * 64;

  __shared__ unsigned short As[2 * 256 * 64];
  __shared__ unsigned short Bs[2 * 256 * 64];

  f32x4 acc[8][4] = {};

  const int srow = lane >> 3;
  const int sswz = ((lane & 7) ^ srow) * 8;
  const unsigned short* gA = A + (size_t)(bm0 + w * 32 + srow) * 1024 + sswz;
  const unsigned short* gB = Wt + (size_t)(bn0g + w * 32 + srow) * 1024 + sswz;

  kloop256(gA, gB, As, Bs, w, fm, quad, acc);

  float bv[4];
  #pragma unroll
  for (int nt = 0; nt < 4; nt++) bv[nt] = bias[bn0 + wn64 + nt * 16 + fm];

  #pragma unroll
  for (int mt = 0; mt < 8; mt++) {
    #pragma unroll
    for (int nt = 0; nt < 4; nt++) {
      #pragma unroll
      for (int r = 0; r < 4; r++) {
        int row = bm0 + wm128 + mt * 16 + quad * 4 + r;   // = b*2048+s
        int col = bn0 + wn64 + nt * 16 + fm;              // = h*64+hd (within z matrix)
        float v = (acc[mt][nt][r] + bv[nt]) * scale;
        int b = row >> 11, s = row & 2047, h = col >> 6, hd = col & 63;
        if (z < 2)
          out[(((b << 4) + h) * 2048 + s) * 64 + hd] = f2bf(v);
        else
          out[(((b << 4) + h) * 64 + hd) * 2048 + s] = f2bf(v);
      }
    }
  }
}

// ---------------- final GEMM: out fp32 = heads * Wo^T + bo (256x256 8-phase) -------------
// Grid 128 blocks (32x4), 512 threads; all co-resident in one pass.
__global__ __launch_bounds__(512, 2) void gemm_out(const unsigned short* __restrict__ A,
                                                   const unsigned short* __restrict__ Bt,
                                                   const float* __restrict__ bias,
                                                   float* __restrict__ out) {
  const int bid = blockIdx.x;
  const int bx = bid & 3, by = bid >> 2;
  const int bm0 = by * 256, bn0 = bx * 256;

  const int tid = threadIdx.x;
  const int lane = tid & 63, w = tid >> 6;
  const int fm = lane & 15, quad = lane >> 4;
  const int wm128 = (w >> 2) * 128, wn64 = (w & 3) * 64;

  __shared__ unsigned short As[2 * 256 * 64];
  __shared__ unsigned short Bs[2 * 256 * 64];

  f32x4 acc[8][4] = {};

  const int srow = lane >> 3;
  const int sswz = ((lane & 7) ^ srow) * 8;
  const unsigned short* gA = A + (size_t)(bm0 + w * 32 + srow) * 1024 + sswz;
  const unsigned short* gB = Bt + (size_t)(bn0 + w * 32 + srow) * 1024 + sswz;

  kloop256(gA, gB, As, Bs, w, fm, quad, acc);

  float bv[4];
  #pragma unroll
  for (int nt = 0; nt < 4; nt++) bv[nt] = bias[bn0 + wn64 + nt * 16 + fm];

  #pragma unroll
  for (int mt = 0; mt < 8; mt++)
    #pragma unroll
    for (int nt = 0; nt < 4; nt++)
      #pragma unroll
      for (int r = 0; r < 4; r++) {
        int row = bm0 + wm128 + mt * 16 + quad * 4 + r;
        int col = bn0 + wn64 + nt * 16 + fm;
        out[(size_t)row * 1024 + col] = acc[mt][nt][r] + bv[nt];
      }
}

// ---------------- flash attention (swapped-QK^T, in-register softmax, K/V dbuf) -----------
// Grid (bh=64, qt=16). Double-buffered K/V (32 KB LDS), one barrier/step.
// Q pre-scaled by 0.125*log2e; p = exp2(qk).
// Swapped QK^T: s = mfma(K, Q) -> S^T; packed pw words ARE the PV A-frag in permuted
// key order pi. Vs stored in SIGMA-PERMUTED key order (R7, verified: bank conflicts
// 8.39M -> ~0) staged via 8x global_load_lds size=4; PV reads ONE conflict-free
// ds_read_b128 at chunk ((ks*4+quad)^fsw) delivering exactly pi order.
__global__ __launch_bounds__(256, 4) void k_attn(const unsigned short* __restrict__ q,
                                                 const unsigned short* __restrict__ k,
                                                 const unsigned short* __restrict__ vt,
                                                 unsigned short* __restrict__ heads) {
  const int tid = threadIdx.x, lane = tid & 63, w = tid >> 6;
  const int fm = lane & 15, quad = lane >> 4, k0 = quad * 8;
  const int bh = blockIdx.x, qt = blockIdx.y;
  const int b = bh >> 4, h = bh & 15;
  const unsigned short* qg = q + (size_t)bh * 2048 * 64;
  const unsigned short* kg = k + (size_t)bh * 2048 * 64;
  const unsigned short* vg = vt + (size_t)bh * 64 * 2048;

  __shared__ unsigned short Ks[2 * 64 * 64];
  __shared__ unsigned short Vs[2 * 64 * 64];

  const int sr = lane >> 3;
  const int sswz = ((lane & 7) ^ sr) * 8;
  const unsigned short* gK = kg + (w * 16 + sr) * 64 + sswz;            // +kb*4096/iter
  unsigned short* lK = Ks + w * 1024;
  unsigned short* lV = Vs + w * 1024;

  // per-lane V source pointers for sigma-ordered 4B staging (instr i covers rows 2i,2i+1)
  const unsigned short* gVp[8];
  {
    const int rhalf = lane >> 5;               // 0/1: which of the 2 rows this instr
    const int cpos = (lane & 31) >> 2;         // stored chunk position 0..7
    const int jlo = (lane & 1) * 2;            // (j&3): j = 2*(lane&3)
    const int jhi = ((lane >> 1) & 1) * 16;    // (j>=4)*16
    #pragma unroll
    for (int i = 0; i < 8; i++) {
      int rr = 2 * i + rhalf;                  // row 0..15 within wave's 16 rows
      int cc = cpos ^ (rr & 7);                // global chunk (XOR layout, read uses fm&7)
      int koff = (cc & 4) * 8 + (cc & 3) * 4 + jlo + jhi;   // sigma_cc(j)
      gVp[i] = vg + (size_t)(w * 16 + rr) * 2048 + koff;
    }
  }

  bf16x8 aq[2][2];
  #pragma unroll
  for (int mt = 0; mt < 2; mt++)
    #pragma unroll
    for (int kh = 0; kh < 2; kh++)
      aq[mt][kh] = *(const bf16x8*)&qg[(qt * 128 + w * 32 + mt * 16 + fm) * 64 + kh * 32 + k0];

  bf16x8 onesf;
  #pragma unroll
  for (int i = 0; i < 8; i++) onesf[i] = (short)0x3F80;

  f32x4 o[2][4] = {};
  f32x4 la[2] = {};
  const f32x4 zf = {0.f, 0.f, 0.f, 0.f};   // hoisted zero-C
  const int fsw = fm & 7;

  // prologue: stage kb=0 into buf0
  gl2l16(gK, lK);
  gl2l16(gK + 512, lK + 512);
  #pragma unroll
  for (int i = 0; i < 8; i++) gl2l4(gVp[i], lV + i * 128);
  __syncthreads();

  for (int kb = 0; kb < 32; kb++) {
    const int cur = kb & 1;
    if (kb < 31) {
      const int nb = cur ^ 1;
      gl2l16(gK + (kb + 1) * 4096,       lK + nb * 4096);
      gl2l16(gK + (kb + 1) * 4096 + 512, lK + nb * 4096 + 512);
      #pragma unroll
      for (int i = 0; i < 8; i++)
        gl2l4(gVp[i] + (kb + 1) * 64, lV + nb * 4096 + i * 128);
    }
    const unsigned short* Kb = Ks + cur * 4096;
    const unsigned short* Vb = Vs + cur * 4096;

    // S^T = K Q^T (operand-swapped): per nt, 4 MFMA, then exp2+pack immediately.
    unsigned int pw[2][8];   // [mt][word]; all indices compile-time
    #pragma unroll
    for (int nt = 0; nt < 4; nt++) {
      bf16x8 bK0 = *(const bf16x8*)&Kb[(nt * 16 + fm) * 64 + ((quad ^ fsw) * 8)];
      f32x4 s0 = MFMA16(bK0, aq[0][0], zf, 0, 0, 0);
      f32x4 s1 = MFMA16(bK0, aq[1][0], zf, 0, 0, 0);
      bf16x8 bK1 = *(const bf16x8*)&Kb[(nt * 16 + fm) * 64 + (((4 + quad) ^ fsw) * 8)];
      s0 = MFMA16(bK1, aq[0][1], s0, 0, 0, 0);
      s1 = MFMA16(bK1, aq[1][1], s1, 0, 0, 0);
      pw[0][nt * 2 + 0] = pkbf(__builtin_amdgcn_exp2f(s0[0]), __builtin_amdgcn_exp2f(s0[1]));
      pw[0][nt * 2 + 1] = pkbf(__builtin_amdgcn_exp2f(s0[2]), __builtin_amdgcn_exp2f(s0[3]));
      pw[1][nt * 2 + 0] = pkbf(__builtin_amdgcn_exp2f(s1[0]), __builtin_amdgcn_exp2f(s1[1]));
      pw[1][nt * 2 + 1] = pkbf(__builtin_amdgcn_exp2f(s1[2]), __builtin_amdgcn_exp2f(s1[3]));
    }

    // P A-fragments (pi key order), directly from packed words.
    bf16x8 ap0k0 = pack4(pw[0][0], pw[0][1], pw[0][2], pw[0][3]);
    bf16x8 ap0k1 = pack4(pw[0][4], pw[0][5], pw[0][6], pw[0][7]);
    bf16x8 ap1k0 = pack4(pw[1][0], pw[1][1], pw[1][2], pw[1][3]);
    bf16x8 ap1k1 = pack4(pw[1][4], pw[1][5], pw[1][6], pw[1][7]);

    // O += P V ; l += P * ones  (V b128 delivers pi order via sigma layout)
    #pragma unroll
    for (int ks = 0; ks < 2; ks++) {
      bf16x8 a0 = ks ? ap0k1 : ap0k0;
      bf16x8 a1 = ks ? ap1k1 : ap1k0;
      la[0] = MFMA16(a0, onesf, la[0], 0, 0, 0);
      la[1] = MFMA16(a1, onesf, la[1], 0, 0, 0);
      #pragma unroll
      for (int ntO = 0; ntO < 4; ntO++) {
        bf16x8 bV = *(const bf16x8*)&Vb[(ntO * 16 + fm) * 64 + (((ks * 4 + quad) ^ fsw) * 8)];
        o[0][ntO] = MFMA16(a0, bV, o[0][ntO], 0, 0, 0);
        o[1][ntO] = MFMA16(a1, bV, o[1][ntO], 0, 0, 0);
      }
    }
    __syncthreads();   // drains the just-issued stage; protects buffer flip
  }

  // normalize + store: la[mt][r] holds l for row quad*4+r (same C-layout as o)
  #pragma unroll
  for (int mt = 0; mt < 2; mt++)
    #pragma unroll
    for (int r = 0; r < 4; r++) {
      float inv = 1.0f / la[mt][r];
      int srw = qt * 128 + w * 32 + mt * 16 + quad * 4 + r;
      #pragma unroll
      for (int nt = 0; nt < 4; nt++)
        heads[(size_t)(b * 2048 + srw) * 1024 + h * 64 + nt * 16 + fm] =
            f2bf(o[mt][nt][r] * inv);
    }
}

extern "C" void kernel_launch(void* const* d_in, const int* in_sizes, int n_in,
                              void* d_out, int out_size, void* d_ws, size_t ws_size,
                              hipStream_t stream) {
  const float* x  = (const float*)d_in[0];
  const float* Wq = (const float*)d_in[1];
  const float* bq = (const float*)d_in[2];
  const float* Wk = (const float*)d_in[3];
  const float* bk = (const float*)d_in[4];
  const float* Wv = (const float*)d_in[5];
  const float* bv = (const float*)d_in[6];
  const float* Wo = (const float*)d_in[7];
  const float* bo = (const float*)d_in[8];
  float* out = (float*)d_out;

  char* ws = (char*)d_ws;
  unsigned short* xb  = (unsigned short*)(ws);
  unsigned short* wtq = (unsigned short*)(ws + (16u << 20));
  unsigned short* wtk = (unsigned short*)(ws + (18u << 20));
  unsigned short* wtv = (unsigned short*)(ws + (20u << 20));
  unsigned short* wto = (unsigned short*)(ws + (22u << 20));
  unsigned short* qb  = (unsigned short*)(ws + (24u << 20));
  unsigned short* kb2 = (unsigned short*)(ws + (40u << 20));
  unsigned short* vtb = (unsigned short*)(ws + (56u << 20));
  unsigned short* hb  = (unsigned short*)(ws + (72u << 20));

  k_prep<<<12288, 256, 0, stream>>>(x, xb, Wq, Wk, Wv, Wo, wtq, wtk, wtv, wto);

  const float qscale = 0.125f * 1.44269504088896f;  // 1/sqrt(64) * log2(e)
  gemm_qkv<<<384, 512, 0, stream>>>(xb, wtq, bq, bk, bv, qb, kb2, vtb, qscale);

  k_attn<<<dim3(64, 16), 256, 0, stream>>>(qb, kb2, vtb, hb);

  gemm_out<<<128, 512, 0, stream>>>(hb, wto, bo, out);
}

// Round 10
// 278.695 us; speedup vs baseline: 1.1236x; 1.1236x over previous
//
#include <hip/hip_runtime.h>

// B=4, S=2048, D=1024, H=16, Hd=64. All matmuls bf16 MFMA (16x16x32), fp32 accum.
// ws layout (bytes):
//   xb    @ 0   : bf16 x [8192,1024]            16 MB
//   wt[4] @ 16M : bf16 W^T (q,k,v,o) [1024,1024] 2 MB each (q,k,v CONTIGUOUS = [3072][1024])
//   qb    @ 24M : bf16 Q*(0.125*log2e) [bh][s][hd] 16 MB
//   kb    @ 40M : bf16 K [bh][s][hd]             16 MB
//   vtb   @ 56M : bf16 V^T [bh][hd][s]           16 MB
//   hb    @ 72M : bf16 heads [b*s][1024]         16 MB
//
// R8 lesson: 256^2 8-phase port regressed (123 us, 2 occupancy passes at 1 block/CU +
// insufficient prefetch distance with no co-resident blocks). For K=1024 shapes the
// 2-barrier kloop64 + many blocks is the measured local optimum. Do not re-attempt
// deep pipelining here without solving the pass-quantization problem first.

typedef __attribute__((ext_vector_type(8))) short bf16x8;
typedef __attribute__((ext_vector_type(4))) float f32x4;
typedef __attribute__((ext_vector_type(4))) unsigned int u32x4;

#define MFMA16 __builtin_amdgcn_mfma_f32_16x16x32_bf16

__device__ __forceinline__ unsigned short f2bf(float f) {
  unsigned int u = __float_as_uint(f);
  u += 0x7fff + ((u >> 16) & 1);   // RNE
  return (unsigned short)(u >> 16);
}

// pack 2 f32 -> 1 u32 of 2 bf16, EXPLICIT order: bf16(lo) in [15:0], bf16(hi) in [31:16].
// Round-half-up (+0x8000). v_perm_b32 sel 0x07060302 = {hi.top16, lo.top16}.
__device__ __forceinline__ unsigned int pkbf(float lo, float hi) {
  unsigned int a = __float_as_uint(lo) + 0x8000u;
  unsigned int b = __float_as_uint(hi) + 0x8000u;
  return __builtin_amdgcn_perm(b, a, 0x07060302u);
}

__device__ __forceinline__ bf16x8 pack4(unsigned int a, unsigned int b,
                                        unsigned int c, unsigned int d) {
  union { u32x4 u; bf16x8 v; } t;
  t.u = (u32x4){a, b, c, d};
  return t.v;
}

// async global->LDS; LDS dest = wave-uniform base + lane*size
__device__ __forceinline__ void gl2l16(const unsigned short* g, unsigned short* l) {
  __builtin_amdgcn_global_load_lds((const __attribute__((address_space(1))) void*)g,
                                   (__attribute__((address_space(3))) void*)l, 16, 0, 0);
}
__device__ __forceinline__ void gl2l4(const unsigned short* g, unsigned short* l) {
  __builtin_amdgcn_global_load_lds((const __attribute__((address_space(1))) void*)g,
                                   (__attribute__((address_space(3))) void*)l, 4, 0, 0);
}

// ---------------- fused prep: convert x + transpose weights (one launch) ----------------
__global__ __launch_bounds__(256) void k_prep(const float* __restrict__ x,
                                              unsigned short* __restrict__ xb,
                                              const float* w0, const float* w1,
                                              const float* w2, const float* w3,
                                              unsigned short* o0, unsigned short* o1,
                                              unsigned short* o2, unsigned short* o3) {
  const int bid = blockIdx.x, tid = threadIdx.x;
  if (bid < 8192) {
    int i = (bid * 256 + tid) * 4;
    float4 v = *(const float4*)(x + i);
    ushort4 u;
    u.x = f2bf(v.x); u.y = f2bf(v.y); u.z = f2bf(v.z); u.w = f2bf(v.w);
    *(ushort4*)(xb + i) = u;
  } else {
    __shared__ float t[32][33];
    int tt = bid - 8192;
    int z = tt >> 10, rem = tt & 1023;
    const float* W = z == 0 ? w0 : z == 1 ? w1 : z == 2 ? w2 : w3;
    unsigned short* O = z == 0 ? o0 : z == 1 ? o1 : z == 2 ? o2 : o3;
    int e0 = (rem & 31) * 32, d0 = (rem >> 5) * 32;
    int tx = tid & 31, ty = tid >> 5;   // 32 x 8
    #pragma unroll
    for (int i = 0; i < 4; i++)
      t[ty + i * 8][tx] = W[(d0 + ty + i * 8) * 1024 + e0 + tx];
    __syncthreads();
    #pragma unroll
    for (int i = 0; i < 4; i++)
      O[(e0 + ty + i * 8) * 1024 + d0 + tx] = f2bf(t[tx][ty + i * 8]);
  }
}

// ---------------- shared GEMM K-loop: single-buffer, 2 barriers/K-step (R2/R7 proven) -----
// 32 KB LDS; cross-block wave overlap (m114) hides the barrier drain.
__device__ __forceinline__ void kloop64(const unsigned short* __restrict__ gA,
                                        const unsigned short* __restrict__ gB,
                                        unsigned short* As, unsigned short* Bs,
                                        int w, int fm, int quad, int wr, int wc,
                                        f32x4 (&acc)[4][4]) {
  const int fsw = fm & 7;
  const int cs0 = (quad ^ fsw) * 8;          // kh=0 chunk offset
  const int cs1 = ((quad + 4) ^ fsw) * 8;    // kh=1 chunk offset
  unsigned short* lA = As + w * 2048;
  unsigned short* lB = Bs + w * 2048;

  for (int kb = 0; kb < 1024; kb += 64) {
    __syncthreads();
    #pragma unroll
    for (int i = 0; i < 4; i++) {
      gl2l16(gA + kb + i * 8192, lA + i * 512);
      gl2l16(gB + kb + i * 8192, lB + i * 512);
    }
    __syncthreads();
    #pragma unroll
    for (int kh = 0; kh < 2; kh++) {
      const int cs = kh ? cs1 : cs0;
      bf16x8 af[4], bfr[4];
      #pragma unroll
      for (int mt = 0; mt < 4; mt++)
        af[mt] = *(const bf16x8*)&As[(wr + mt * 16 + fm) * 64 + cs];
      #pragma unroll
      for (int nt = 0; nt < 4; nt++)
        bfr[nt] = *(const bf16x8*)&Bs[(wc + nt * 16 + fm) * 64 + cs];
      #pragma unroll
      for (int mt = 0; mt < 4; mt++)
        #pragma unroll
        for (int nt = 0; nt < 4; nt++)
          acc[mt][nt] = MFMA16(af[mt], bfr[nt], acc[mt][nt], 0, 0, 0);
    }
  }
}

// ---------------- fused QKV GEMM: one N=3072 GEMM over contiguous W^T block ----------------
// Grid: 1536 blocks 1D, R2-equivalent mapping (measured fastest): xcd=bid&7 = col tile
// (mod 8); by advances in lockstep across XCDs (all XCDs stream the SAME A row-panel
// window). phase = c>>6 selects the matrix (Q,K,V sequential), bx = xcd + 8*phase.
__global__ __launch_bounds__(256) void gemm_qkv(const unsigned short* __restrict__ A,
                                                const unsigned short* __restrict__ Wt,
                                                const float* __restrict__ biq,
                                                const float* __restrict__ bik,
                                                const float* __restrict__ biv,
                                                unsigned short* __restrict__ oq,
                                                unsigned short* __restrict__ ok,
                                                unsigned short* __restrict__ ov,
                                                float qscale) {
  const int bid = blockIdx.x;
  const int xcd = bid & 7, c = bid >> 3;        // c in [0,192)
  const int by = c & 63;                        // row panel [0,64), lockstep across XCDs
  const int phase = c >> 6;                     // {0,1,2} = Q,K,V
  const int bx = xcd + phase * 8;               // col tile [0,24)
  const int bm0 = by * 128;
  const int bn0g = bx * 128;                    // global col in [0,3072)
  const int z = phase, bn0 = bn0g & 1023;

  const float* bias = z == 0 ? biq : z == 1 ? bik : biv;
  unsigned short* out = z == 0 ? oq : z == 1 ? ok : ov;
  const float scale = z == 0 ? qscale : 1.0f;

  const int tid = threadIdx.x;
  const int lane = tid & 63, w = tid >> 6;
  const int wr = (w >> 1) * 64, wc = (w & 1) * 64;
  const int fm = lane & 15, quad = lane >> 4;

  __shared__ unsigned short As[128 * 64];
  __shared__ unsigned short Bs[128 * 64];

  f32x4 acc[4][4] = {};

  const int srow = lane >> 3;                 // 0..7
  const int sswz = ((lane & 7) ^ srow) * 8;
  const unsigned short* gA = A + (size_t)(bm0 + w * 32 + srow) * 1024 + sswz;
  const unsigned short* gB = Wt + (size_t)(bn0g + w * 32 + srow) * 1024 + sswz;

  kloop64(gA, gB, As, Bs, w, fm, quad, wr, wc, acc);

  float bv[4];
  #pragma unroll
  for (int nt = 0; nt < 4; nt++) bv[nt] = bias[bn0 + wc + nt * 16 + fm];

  #pragma unroll
  for (int mt = 0; mt < 4; mt++) {
    #pragma unroll
    for (int nt = 0; nt < 4; nt++) {
      #pragma unroll
      for (int r = 0; r < 4; r++) {
        int row = bm0 + wr + mt * 16 + quad * 4 + r;   // = b*2048+s
        int col = bn0 + wc + nt * 16 + fm;             // = h*64+hd
        float v = (acc[mt][nt][r] + bv[nt]) * scale;
        int b = row >> 11, s = row & 2047, h = col >> 6, hd = col & 63;
        if (z < 2)
          out[(((b << 4) + h) * 2048 + s) * 64 + hd] = f2bf(v);
        else
          out[(((b << 4) + h) * 64 + hd) * 2048 + s] = f2bf(v);
      }
    }
  }
}

// ---------------- final GEMM: out fp32 = heads * Wo^T + bo ----------------
// Grid: 512 blocks 1D. XCD swizzle: xcd owns 8 y-panels x all 8 x-tiles, x-fastest;
// B (2 MB) stays L2-resident per XCD.
__global__ __launch_bounds__(256) void gemm_out(const unsigned short* __restrict__ A,
                                                const unsigned short* __restrict__ Bt,
                                                const float* __restrict__ bias,
                                                float* __restrict__ out) {
  const int bid = blockIdx.x;
  const int xcd = bid & 7, c = bid >> 3;        // c in [0,64)
  const int by = xcd * 8 + (c >> 3);            // [0,64)
  const int bx = c & 7;                         // [0,8)
  const int bm0 = by * 128, bn0 = bx * 128;

  const int tid = threadIdx.x;
  const int lane = tid & 63, w = tid >> 6;
  const int wr = (w >> 1) * 64, wc = (w & 1) * 64;
  const int fm = lane & 15, quad = lane >> 4;

  __shared__ unsigned short As[128 * 64];
  __shared__ unsigned short Bs[128 * 64];

  f32x4 acc[4][4] = {};

  const int srow = lane >> 3;
  const int sswz = ((lane & 7) ^ srow) * 8;
  const unsigned short* gA = A + (size_t)(bm0 + w * 32 + srow) * 1024 + sswz;
  const unsigned short* gB = Bt + (size_t)(bn0 + w * 32 + srow) * 1024 + sswz;

  kloop64(gA, gB, As, Bs, w, fm, quad, wr, wc, acc);

  float bv[4];
  #pragma unroll
  for (int nt = 0; nt < 4; nt++) bv[nt] = bias[bn0 + wc + nt * 16 + fm];

  #pragma unroll
  for (int mt = 0; mt < 4; mt++)
    #pragma unroll
    for (int nt = 0; nt < 4; nt++)
      #pragma unroll
      for (int r = 0; r < 4; r++) {
        int row = bm0 + wr + mt * 16 + quad * 4 + r;
        int col = bn0 + wc + nt * 16 + fm;
        out[(size_t)row * 1024 + col] = acc[mt][nt][r] + bv[nt];
      }
}

// ---------------- flash attention (swapped-QK^T, in-reg softmax, K/V dbuf, 8 waves) -------
// R9: 8-wave blocks, 256 q-rows each; grid (bh=64, qt=8) = 512 blocks. Same LDS image
// (Ks/Vs [64][64], 32 KB dbuf) but each K/V tile is now staged by half as many blocks
// -> total staging work and K/V L2 traffic halved. 2 blocks/CU = 16 waves/CU (as before).
// Per wave per step: 1 gl2l16 (8 K-rows) + 4 gl2l4 (8 sigma-V rows).
// Swapped QK^T: s = mfma(K, Q) -> S^T; packed pw words ARE the PV A-frag in permuted
// key order pi. Vs stored in SIGMA-PERMUTED key order (R7, verified conflict-free);
// PV reads ONE ds_read_b128 at chunk ((ks*4+quad)^fsw) delivering exactly pi order.
__global__ __launch_bounds__(512, 4) void k_attn(const unsigned short* __restrict__ q,
                                                 const unsigned short* __restrict__ k,
                                                 const unsigned short* __restrict__ vt,
                                                 unsigned short* __restrict__ heads) {
  const int tid = threadIdx.x, lane = tid & 63, w = tid >> 6;   // w in [0,8)
  const int fm = lane & 15, quad = lane >> 4, k0 = quad * 8;
  const int bh = blockIdx.x, qt = blockIdx.y;
  const int b = bh >> 4, h = bh & 15;
  const unsigned short* qg = q + (size_t)bh * 2048 * 64;
  const unsigned short* kg = k + (size_t)bh * 2048 * 64;
  const unsigned short* vg = vt + (size_t)bh * 64 * 2048;

  __shared__ unsigned short Ks[2 * 64 * 64];
  __shared__ unsigned short Vs[2 * 64 * 64];

  const int sr = lane >> 3;
  const int sswz = ((lane & 7) ^ sr) * 8;
  const unsigned short* gK = kg + (w * 8 + sr) * 64 + sswz;             // +kb*4096/iter
  unsigned short* lK = Ks + w * 512;
  unsigned short* lV = Vs + w * 512;

  // per-lane V source pointers for sigma-ordered 4B staging (instr i covers rows 2i,2i+1
  // of this wave's 8-row region)
  const unsigned short* gVp[4];
  {
    const int rhalf = lane >> 5;               // 0/1: which of the 2 rows this instr
    const int cpos = (lane & 31) >> 2;         // stored chunk position 0..7
    const int jlo = (lane & 1) * 2;            // (j&3): j = 2*(lane&3)
    const int jhi = ((lane >> 1) & 1) * 16;    // (j>=4)*16
    #pragma unroll
    for (int i = 0; i < 4; i++) {
      int rr = 2 * i + rhalf;                  // row 0..7 within wave's 8 rows
      int cc = cpos ^ (rr & 7);                // global chunk (XOR layout, read uses fm&7)
      int koff = (cc & 4) * 8 + (cc & 3) * 4 + jlo + jhi;   // sigma_cc(j)
      gVp[i] = vg + (size_t)(w * 8 + rr) * 2048 + koff;
    }
  }

  bf16x8 aq[2][2];
  #pragma unroll
  for (int mt = 0; mt < 2; mt++)
    #pragma unroll
    for (int kh = 0; kh < 2; kh++)
      aq[mt][kh] = *(const bf16x8*)&qg[(qt * 256 + w * 32 + mt * 16 + fm) * 64 + kh * 32 + k0];

  bf16x8 onesf;
  #pragma unroll
  for (int i = 0; i < 8; i++) onesf[i] = (short)0x3F80;

  f32x4 o[2][4] = {};
  f32x4 la[2] = {};
  const f32x4 zf = {0.f, 0.f, 0.f, 0.f};   // hoisted zero-C
  const int fsw = fm & 7;

  // prologue: stage kb=0 into buf0
  gl2l16(gK, lK);
  #pragma unroll
  for (int i = 0; i < 4; i++) gl2l4(gVp[i], lV + i * 128);
  __syncthreads();

  for (int kb = 0; kb < 32; kb++) {
    const int cur = kb & 1;
    if (kb < 31) {
      const int nb = cur ^ 1;
      gl2l16(gK + (kb + 1) * 4096, lK + nb * 4096);
      #pragma unroll
      for (int i = 0; i < 4; i++)
        gl2l4(gVp[i] + (kb + 1) * 64, lV + nb * 4096 + i * 128);
    }
    const unsigned short* Kb = Ks + cur * 4096;
    const unsigned short* Vb = Vs + cur * 4096;

    // S^T = K Q^T (operand-swapped): per nt, 4 MFMA, then exp2+pack immediately.
    unsigned int pw[2][8];   // [mt][word]; all indices compile-time
    #pragma unroll
    for (int nt = 0; nt < 4; nt++) {
      bf16x8 bK0 = *(const bf16x8*)&Kb[(nt * 16 + fm) * 64 + ((quad ^ fsw) * 8)];
      f32x4 s0 = MFMA16(bK0, aq[0][0], zf, 0, 0, 0);
      f32x4 s1 = MFMA16(bK0, aq[1][0], zf, 0, 0, 0);
      bf16x8 bK1 = *(const bf16x8*)&Kb[(nt * 16 + fm) * 64 + (((4 + quad) ^ fsw) * 8)];
      s0 = MFMA16(bK1, aq[0][1], s0, 0, 0, 0);
      s1 = MFMA16(bK1, aq[1][1], s1, 0, 0, 0);
      pw[0][nt * 2 + 0] = pkbf(__builtin_amdgcn_exp2f(s0[0]), __builtin_amdgcn_exp2f(s0[1]));
      pw[0][nt * 2 + 1] = pkbf(__builtin_amdgcn_exp2f(s0[2]), __builtin_amdgcn_exp2f(s0[3]));
      pw[1][nt * 2 + 0] = pkbf(__builtin_amdgcn_exp2f(s1[0]), __builtin_amdgcn_exp2f(s1[1]));
      pw[1][nt * 2 + 1] = pkbf(__builtin_amdgcn_exp2f(s1[2]), __builtin_amdgcn_exp2f(s1[3]));
    }

    // P A-fragments (pi key order), directly from packed words.
    bf16x8 ap0k0 = pack4(pw[0][0], pw[0][1], pw[0][2], pw[0][3]);
    bf16x8 ap0k1 = pack4(pw[0][4], pw[0][5], pw[0][6], pw[0][7]);
    bf16x8 ap1k0 = pack4(pw[1][0], pw[1][1], pw[1][2], pw[1][3]);
    bf16x8 ap1k1 = pack4(pw[1][4], pw[1][5], pw[1][6], pw[1][7]);

    // O += P V ; l += P * ones  (V b128 delivers pi order via sigma layout)
    #pragma unroll
    for (int ks = 0; ks < 2; ks++) {
      bf16x8 a0 = ks ? ap0k1 : ap0k0;
      bf16x8 a1 = ks ? ap1k1 : ap1k0;
      la[0] = MFMA16(a0, onesf, la[0], 0, 0, 0);
      la[1] = MFMA16(a1, onesf, la[1], 0, 0, 0);
      #pragma unroll
      for (int ntO = 0; ntO < 4; ntO++) {
        bf16x8 bV = *(const bf16x8*)&Vb[(ntO * 16 + fm) * 64 + (((ks * 4 + quad) ^ fsw) * 8)];
        o[0][ntO] = MFMA16(a0, bV, o[0][ntO], 0, 0, 0);
        o[1][ntO] = MFMA16(a1, bV, o[1][ntO], 0, 0, 0);
      }
    }
    __syncthreads();   // drains the just-issued stage; protects buffer flip
  }

  // normalize + store: la[mt][r] holds l for row quad*4+r (same C-layout as o)
  #pragma unroll
  for (int mt = 0; mt < 2; mt++)
    #pragma unroll
    for (int r = 0; r < 4; r++) {
      float inv = 1.0f / la[mt][r];
      int srw = qt * 256 + w * 32 + mt * 16 + quad * 4 + r;
      #pragma unroll
      for (int nt = 0; nt < 4; nt++)
        heads[(size_t)(b * 2048 + srw) * 1024 + h * 64 + nt * 16 + fm] =
            f2bf(o[mt][nt][r] * inv);
    }
}

extern "C" void kernel_launch(void* const* d_in, const int* in_sizes, int n_in,
                              void* d_out, int out_size, void* d_ws, size_t ws_size,
                              hipStream_t stream) {
  const float* x  = (const float*)d_in[0];
  const float* Wq = (const float*)d_in[1];
  const float* bq = (const float*)d_in[2];
  const float* Wk = (const float*)d_in[3];
  const float* bk = (const float*)d_in[4];
  const float* Wv = (const float*)d_in[5];
  const float* bv = (const float*)d_in[6];
  const float* Wo = (const float*)d_in[7];
  const float* bo = (const float*)d_in[8];
  float* out = (float*)d_out;

  char* ws = (char*)d_ws;
  unsigned short* xb  = (unsigned short*)(ws);
  unsigned short* wtq = (unsigned short*)(ws + (16u << 20));
  unsigned short* wtk = (unsigned short*)(ws + (18u << 20));
  unsigned short* wtv = (unsigned short*)(ws + (20u << 20));
  unsigned short* wto = (unsigned short*)(ws + (22u << 20));
  unsigned short* qb  = (unsigned short*)(ws + (24u << 20));
  unsigned short* kb2 = (unsigned short*)(ws + (40u << 20));
  unsigned short* vtb = (unsigned short*)(ws + (56u << 20));
  unsigned short* hb  = (unsigned short*)(ws + (72u << 20));

  k_prep<<<12288, 256, 0, stream>>>(x, xb, Wq, Wk, Wv, Wo, wtq, wtk, wtv, wto);

  const float qscale = 0.125f * 1.44269504088896f;  // 1/sqrt(64) * log2(e)
  gemm_qkv<<<1536, 256, 0, stream>>>(xb, wtq, bq, bk, bv, qb, kb2, vtb, qscale);

  k_attn<<<dim3(64, 8), 512, 0, stream>>>(qb, kb2, vtb, hb);

  gemm_out<<<512, 256, 0, stream>>>(hb, wto, bo, out);
}